// Round 1
// baseline (1481.386 us; speedup 1.0000x reference)
//
#include <hip/hip_runtime.h>
#include <hip/hip_bf16.h>

#define N_NODES 8192
#define F_IN    512
#define DIM     256
#define NCLS    40

// ---------------------------------------------------------------------------
// Generic fp32 tiled GEMM: C = A * B (+bias), A[M,K] row-major.
// BT=false: B[K,N] row-major.  BT=true: B[N,K] row-major (computes A*B^T).
// LDS tiles stored K-major: As[BK][BM], Bs[BK][BN].
// ---------------------------------------------------------------------------
template<int BM, int BN, int BK, int TM, int TN, bool BT>
__global__ __launch_bounds__(256) void gemm_kernel(
    const float* __restrict__ A, const float* __restrict__ B,
    const float* __restrict__ bias, float* __restrict__ C,
    int M, int N, int K)
{
    static_assert((BM / TM) * (BN / TN) == 256, "256 threads");
    static_assert((BM * BK) % 1024 == 0 && (BK * BN) % 1024 == 0, "tile loads");

    __shared__ float As[BK][BM];
    __shared__ float Bs[BK][BN];

    const int tid = threadIdx.x;
    const int tx  = tid % (BN / TN);
    const int ty  = tid / (BN / TN);
    const int n0  = blockIdx.x * BN;
    const int m0  = blockIdx.y * BM;

    float acc[TM][TN] = {};

    for (int k0 = 0; k0 < K; k0 += BK) {
        // ---- load A tile (BM x BK), store transposed into As[k][m]
        #pragma unroll
        for (int i = tid * 4; i < BM * BK; i += 1024) {
            int r = i / BK, c = i % BK;
            float4 v = *(const float4*)(A + (size_t)(m0 + r) * K + k0 + c);
            As[c + 0][r] = v.x; As[c + 1][r] = v.y;
            As[c + 2][r] = v.z; As[c + 3][r] = v.w;
        }
        // ---- load B tile
        if (!BT) {
            #pragma unroll
            for (int i = tid * 4; i < BK * BN; i += 1024) {
                int r = i / BN, c = i % BN;
                *(float4*)&Bs[r][c] =
                    *(const float4*)(B + (size_t)(k0 + r) * N + n0 + c);
            }
        } else {
            #pragma unroll
            for (int i = tid * 4; i < BN * BK; i += 1024) {
                int r = i / BK, c = i % BK;
                float4 v = *(const float4*)(B + (size_t)(n0 + r) * K + k0 + c);
                Bs[c + 0][r] = v.x; Bs[c + 1][r] = v.y;
                Bs[c + 2][r] = v.z; Bs[c + 3][r] = v.w;
            }
        }
        __syncthreads();

        #pragma unroll
        for (int k = 0; k < BK; ++k) {
            float a[TM], b[TN];
            #pragma unroll
            for (int i = 0; i < TM; ++i) a[i] = As[k][ty * TM + i];
            #pragma unroll
            for (int j = 0; j < TN; ++j) b[j] = Bs[k][tx * TN + j];
            #pragma unroll
            for (int i = 0; i < TM; ++i)
                #pragma unroll
                for (int j = 0; j < TN; ++j)
                    acc[i][j] += a[i] * b[j];
        }
        __syncthreads();
    }

    // ---- epilogue
    #pragma unroll
    for (int i = 0; i < TM; ++i) {
        const int m = m0 + ty * TM + i;
        #pragma unroll
        for (int j = 0; j < TN; ++j) {
            const int n = n0 + tx * TN + j;
            float v = acc[i][j];
            if (bias) v += bias[n];
            C[(size_t)m * N + n] = v;
        }
    }
}

// ---------------------------------------------------------------------------
// Row LayerNorm in place over last dim (=256), no affine. One block per row.
// ---------------------------------------------------------------------------
__global__ __launch_bounds__(256) void layernorm_kernel(float* __restrict__ X)
{
    const int row = blockIdx.x;
    const int t = threadIdx.x;
    float x = X[(size_t)row * DIM + t];

    float s1 = x, s2 = x * x;
    #pragma unroll
    for (int o = 32; o; o >>= 1) {
        s1 += __shfl_xor(s1, o);
        s2 += __shfl_xor(s2, o);
    }
    __shared__ float r1[4], r2[4];
    const int wid = t >> 6;
    if ((t & 63) == 0) { r1[wid] = s1; r2[wid] = s2; }
    __syncthreads();
    const float sum = r1[0] + r1[1] + r1[2] + r1[3];
    const float ssq = r2[0] + r2[1] + r2[2] + r2[3];
    const float mean = sum * (1.0f / DIM);
    const float var  = ssq * (1.0f / DIM) - mean * mean;
    X[(size_t)row * DIM + t] = (x - mean) * rsqrtf(var + 1e-5f);
}

// ---------------------------------------------------------------------------
// Row softmax in place over 8192 columns. One block (1024 thr) per row;
// each thread keeps its 8 elements in registers. One read + one write.
// ---------------------------------------------------------------------------
__global__ __launch_bounds__(1024) void softmax_kernel(float* __restrict__ S)
{
    const int row = blockIdx.x;
    float* rp = S + (size_t)row * N_NODES;
    const int t = threadIdx.x;

    float4 v0 = *(const float4*)(rp + t * 8);
    float4 v1 = *(const float4*)(rp + t * 8 + 4);
    float x[8] = {v0.x, v0.y, v0.z, v0.w, v1.x, v1.y, v1.z, v1.w};

    float m = x[0];
    #pragma unroll
    for (int i = 1; i < 8; ++i) m = fmaxf(m, x[i]);
    #pragma unroll
    for (int o = 32; o; o >>= 1) m = fmaxf(m, __shfl_xor(m, o));

    __shared__ float redm[16], reds[16];
    const int wid = t >> 6;
    if ((t & 63) == 0) redm[wid] = m;
    __syncthreads();
    float gm = redm[0];
    #pragma unroll
    for (int i = 1; i < 16; ++i) gm = fmaxf(gm, redm[i]);

    float e[8], s = 0.0f;
    #pragma unroll
    for (int i = 0; i < 8; ++i) { e[i] = __expf(x[i] - gm); s += e[i]; }
    #pragma unroll
    for (int o = 32; o; o >>= 1) s += __shfl_xor(s, o);
    if ((t & 63) == 0) reds[wid] = s;
    __syncthreads();
    float gs = 0.0f;
    #pragma unroll
    for (int i = 0; i < 16; ++i) gs += reds[i];
    const float inv = 1.0f / gs;

    v0 = make_float4(e[0] * inv, e[1] * inv, e[2] * inv, e[3] * inv);
    v1 = make_float4(e[4] * inv, e[5] * inv, e[6] * inv, e[7] * inv);
    *(float4*)(rp + t * 8) = v0;
    *(float4*)(rp + t * 8 + 4) = v1;
}

// ---------------------------------------------------------------------------
// SpMM segment-sum: out[n,:] = sum_{e: row[e]==n} w[e] * H[col[e],:]
// edge_row is sorted -> binary search the segment, no atomics.
// One block (256 thr = one feature each) per node.
// ---------------------------------------------------------------------------
__global__ __launch_bounds__(256) void spmm_kernel(
    const float* __restrict__ H, const int* __restrict__ erow,
    const int* __restrict__ ecol, const float* __restrict__ ew,
    float* __restrict__ out, int E)
{
    const int node = blockIdx.x;
    const int t = threadIdx.x;

    int lo = 0, hi = E;
    while (lo < hi) { int mid = (lo + hi) >> 1; if (erow[mid] < node) lo = mid + 1; else hi = mid; }
    const int beg = lo;
    hi = E;
    while (lo < hi) { int mid = (lo + hi) >> 1; if (erow[mid] < node + 1) lo = mid + 1; else hi = mid; }
    const int end = lo;

    float acc = 0.0f;
    for (int e = beg; e < end; ++e) {
        const int col = ecol[e];
        const float w = ew[e];
        acc += w * H[(size_t)col * DIM + t];
    }
    out[(size_t)node * DIM + t] = acc;
}

// ---------------------------------------------------------------------------
// Y[row,:] = (0.5*ZA[row,:] + 0.5*GNN[row,:]) @ W_cls + b_cls
// One block per row; 4 K-quarters x 40 classes in parallel, LDS reduce.
// ---------------------------------------------------------------------------
__global__ __launch_bounds__(256) void blend_cls_kernel(
    const float* __restrict__ ZA, const float* __restrict__ GNN,
    const float* __restrict__ Wc, const float* __restrict__ bc,
    float* __restrict__ Y)
{
    const int row = blockIdx.x;
    const int t = threadIdx.x;
    __shared__ float z[DIM];
    __shared__ float part[4][NCLS];

    z[t] = 0.5f * (ZA[(size_t)row * DIM + t] + GNN[(size_t)row * DIM + t]);
    __syncthreads();

    if (t < 160) {
        const int c = t % NCLS, q = t / NCLS;
        float acc = 0.0f;
        #pragma unroll 4
        for (int d = q * 64; d < q * 64 + 64; ++d)
            acc += z[d] * Wc[d * NCLS + c];
        part[q][c] = acc;
    }
    __syncthreads();
    if (t < NCLS)
        Y[(size_t)row * NCLS + t] =
            part[0][t] + part[1][t] + part[2][t] + part[3][t] + bc[t];
}

// ---------------------------------------------------------------------------
extern "C" void kernel_launch(void* const* d_in, const int* in_sizes, int n_in,
                              void* d_out, int out_size, void* d_ws, size_t ws_size,
                              hipStream_t stream)
{
    const float* X     = (const float*)d_in[0];
    const int*   erow  = (const int*)d_in[1];
    const int*   ecol  = (const int*)d_in[2];
    const float* ew    = (const float*)d_in[3];
    const float* W_emb = (const float*)d_in[4];
    const float* b_emb = (const float*)d_in[5];
    const float* W_q   = (const float*)d_in[6];
    const float* b_q   = (const float*)d_in[7];
    const float* W_k   = (const float*)d_in[8];
    const float* b_k   = (const float*)d_in[9];
    const float* W_v   = (const float*)d_in[10];
    const float* b_v   = (const float*)d_in[11];
    const float* W_g   = (const float*)d_in[12];
    const float* b_g   = (const float*)d_in[13];
    const float* W_c   = (const float*)d_in[14];
    const float* b_c   = (const float*)d_in[15];
    const int E = in_sizes[1];

    float* Y    = (float*)d_out;                      // [N, C]
    float* attn = Y + (size_t)N_NODES * NCLS;         // [N, N]

    const size_t ND = (size_t)N_NODES * DIM;
    float* Z0  = (float*)d_ws;
    float* Q   = Z0 + ND;
    float* Km  = Q + ND;
    float* V   = Km + ND;
    float* H   = V + ND;
    float* ZA  = H + ND;
    float* GNN = ZA + ND;

    // 1. Z0 = X @ W_emb + b_emb          [8192,512]x[512,256]
    gemm_kernel<128, 64, 16, 8, 4, false>
        <<<dim3(DIM / 64, N_NODES / 128), 256, 0, stream>>>(
            X, W_emb, b_emb, Z0, N_NODES, DIM, F_IN);

    // 2. Q',K',V,H = Z0 @ W_* + b_*      [8192,256]x[256,256]
    gemm_kernel<128, 64, 16, 8, 4, false>
        <<<dim3(DIM / 64, N_NODES / 128), 256, 0, stream>>>(
            Z0, W_q, b_q, Q, N_NODES, DIM, DIM);
    gemm_kernel<128, 64, 16, 8, 4, false>
        <<<dim3(DIM / 64, N_NODES / 128), 256, 0, stream>>>(
            Z0, W_k, b_k, Km, N_NODES, DIM, DIM);
    gemm_kernel<128, 64, 16, 8, 4, false>
        <<<dim3(DIM / 64, N_NODES / 128), 256, 0, stream>>>(
            Z0, W_v, b_v, V, N_NODES, DIM, DIM);
    gemm_kernel<128, 64, 16, 8, 4, false>
        <<<dim3(DIM / 64, N_NODES / 128), 256, 0, stream>>>(
            Z0, W_g, b_g, H, N_NODES, DIM, DIM);

    // 3. LayerNorm Q, K (in place)
    layernorm_kernel<<<N_NODES, 256, 0, stream>>>(Q);
    layernorm_kernel<<<N_NODES, 256, 0, stream>>>(Km);

    // 4. scores = Q @ K^T -> attn region of d_out
    gemm_kernel<128, 128, 16, 8, 8, true>
        <<<dim3(N_NODES / 128, N_NODES / 128), 256, 0, stream>>>(
            Q, Km, nullptr, attn, N_NODES, N_NODES, DIM);

    // 5. softmax rows in place
    softmax_kernel<<<N_NODES, 1024, 0, stream>>>(attn);

    // 6. ZA = attn @ V                    [8192,8192]x[8192,256]
    gemm_kernel<64, 64, 16, 4, 4, false>
        <<<dim3(DIM / 64, N_NODES / 64), 256, 0, stream>>>(
            attn, V, nullptr, ZA, N_NODES, DIM, N_NODES);

    // 7. GNN branch: segment_sum(w * H[col], row)
    spmm_kernel<<<N_NODES, 256, 0, stream>>>(H, erow, ecol, ew, GNN, E);

    // 8. blend + classifier -> Y
    blend_cls_kernel<<<N_NODES, 256, 0, stream>>>(ZA, GNN, W_c, b_c, Y);
}

// Round 2
// 750.379 us; speedup vs baseline: 1.9742x; 1.9742x over previous
//
#include <hip/hip_runtime.h>
#include <hip/hip_bf16.h>

#define N_NODES 8192
#define F_IN    512
#define DIM     256
#define NCLS    40

typedef __attribute__((ext_vector_type(8))) short bf16x8;
typedef __attribute__((ext_vector_type(4))) float f32x4;

static __device__ __forceinline__ unsigned short f2bf(float x) {
    __hip_bfloat16 h = __float2bfloat16(x);
    return *reinterpret_cast<unsigned short*>(&h);
}
static __device__ __forceinline__ float bf2f(unsigned short u) {
    union { unsigned int u32; float f; } v; v.u32 = ((unsigned int)u) << 16;
    return v.f;
}

// ---------------------------------------------------------------------------
// Generic fp32 tiled GEMM (kept for the 5 small projections).
// ---------------------------------------------------------------------------
template<int BM, int BN, int BK, int TM, int TN, bool BT>
__global__ __launch_bounds__(256) void gemm_kernel(
    const float* __restrict__ A, const float* __restrict__ B,
    const float* __restrict__ bias, float* __restrict__ C,
    int M, int N, int K)
{
    static_assert((BM / TM) * (BN / TN) == 256, "256 threads");

    __shared__ float As[BK][BM];
    __shared__ float Bs[BK][BN];

    const int tid = threadIdx.x;
    const int tx  = tid % (BN / TN);
    const int ty  = tid / (BN / TN);
    const int n0  = blockIdx.x * BN;
    const int m0  = blockIdx.y * BM;

    float acc[TM][TN] = {};

    for (int k0 = 0; k0 < K; k0 += BK) {
        #pragma unroll
        for (int i = tid * 4; i < BM * BK; i += 1024) {
            int r = i / BK, c = i % BK;
            float4 v = *(const float4*)(A + (size_t)(m0 + r) * K + k0 + c);
            As[c + 0][r] = v.x; As[c + 1][r] = v.y;
            As[c + 2][r] = v.z; As[c + 3][r] = v.w;
        }
        if (!BT) {
            #pragma unroll
            for (int i = tid * 4; i < BK * BN; i += 1024) {
                int r = i / BN, c = i % BN;
                *(float4*)&Bs[r][c] =
                    *(const float4*)(B + (size_t)(k0 + r) * N + n0 + c);
            }
        } else {
            #pragma unroll
            for (int i = tid * 4; i < BN * BK; i += 1024) {
                int r = i / BK, c = i % BK;
                float4 v = *(const float4*)(B + (size_t)(n0 + r) * K + k0 + c);
                Bs[c + 0][r] = v.x; Bs[c + 1][r] = v.y;
                Bs[c + 2][r] = v.z; Bs[c + 3][r] = v.w;
            }
        }
        __syncthreads();

        #pragma unroll
        for (int k = 0; k < BK; ++k) {
            float a[TM], b[TN];
            #pragma unroll
            for (int i = 0; i < TM; ++i) a[i] = As[k][ty * TM + i];
            #pragma unroll
            for (int j = 0; j < TN; ++j) b[j] = Bs[k][tx * TN + j];
            #pragma unroll
            for (int i = 0; i < TM; ++i)
                #pragma unroll
                for (int j = 0; j < TN; ++j)
                    acc[i][j] += a[i] * b[j];
        }
        __syncthreads();
    }

    #pragma unroll
    for (int i = 0; i < TM; ++i) {
        const int m = m0 + ty * TM + i;
        #pragma unroll
        for (int j = 0; j < TN; ++j) {
            const int n = n0 + tx * TN + j;
            float v = acc[i][j];
            if (bias) v += bias[n];
            C[(size_t)m * N + n] = v;
        }
    }
}

// ---------------------------------------------------------------------------
// LayerNorm + split into hi/lo bf16 pair (hi+lo ~ fp32 precision).
// ---------------------------------------------------------------------------
__global__ __launch_bounds__(256) void ln_split_kernel(
    const float* __restrict__ X,
    unsigned short* __restrict__ Hi, unsigned short* __restrict__ Lo)
{
    const int row = blockIdx.x;
    const int t = threadIdx.x;
    float x = X[(size_t)row * DIM + t];

    float s1 = x, s2 = x * x;
    #pragma unroll
    for (int o = 32; o; o >>= 1) {
        s1 += __shfl_xor(s1, o);
        s2 += __shfl_xor(s2, o);
    }
    __shared__ float r1[4], r2[4];
    const int wid = t >> 6;
    if ((t & 63) == 0) { r1[wid] = s1; r2[wid] = s2; }
    __syncthreads();
    const float sum = r1[0] + r1[1] + r1[2] + r1[3];
    const float ssq = r2[0] + r2[1] + r2[2] + r2[3];
    const float mean = sum * (1.0f / DIM);
    const float var  = ssq * (1.0f / DIM) - mean * mean;
    const float y = (x - mean) * rsqrtf(var + 1e-5f);

    const unsigned short h = f2bf(y);
    Hi[(size_t)row * DIM + t] = h;
    Lo[(size_t)row * DIM + t] = f2bf(y - bf2f(h));
}

// ---------------------------------------------------------------------------
// V [8192,256] fp32 -> VT [256,8192] bf16 (LDS transpose).
// ---------------------------------------------------------------------------
__global__ __launch_bounds__(256) void vtrans_kernel(
    const float* __restrict__ V, unsigned short* __restrict__ VT)
{
    __shared__ float tile[64][65];
    const int r0 = blockIdx.x * 64;   // node dim
    const int c0 = blockIdx.y * 64;   // feature dim
    const int t = threadIdx.x;
    #pragma unroll
    for (int i = 0; i < 4; ++i) {
        int r = i * 16 + (t >> 4);
        int c = (t & 15) * 4;
        float4 v = *(const float4*)&V[(size_t)(r0 + r) * DIM + c0 + c];
        tile[r][c] = v.x; tile[r][c + 1] = v.y;
        tile[r][c + 2] = v.z; tile[r][c + 3] = v.w;
    }
    __syncthreads();
    #pragma unroll
    for (int i = 0; i < 4; ++i) {
        int c = i * 16 + (t >> 4);
        int r = (t & 15) * 4;
        ushort4 o;
        o.x = f2bf(tile[r][c]);     o.y = f2bf(tile[r + 1][c]);
        o.z = f2bf(tile[r + 2][c]); o.w = f2bf(tile[r + 3][c]);
        *(ushort4*)&VT[(size_t)(c0 + c) * N_NODES + r0 + r] = o;
    }
}

// ---------------------------------------------------------------------------
// scores = Q @ K^T via split-bf16 3-term MFMA. 128x128 tile, BK=32, 4 waves.
// ---------------------------------------------------------------------------
__global__ __launch_bounds__(256) void qkt_kernel(
    const unsigned short* __restrict__ Qh, const unsigned short* __restrict__ Ql,
    const unsigned short* __restrict__ Kh, const unsigned short* __restrict__ Kl,
    float* __restrict__ S)
{
    __shared__ short Ah[128][40], Al[128][40], Bh[128][40], Bl[128][40];

    // XCD-aware swizzle (4096 % 8 == 0 -> bijective)
    const int bid = blockIdx.x;
    const int wg = (bid & 7) * (4096 / 8) + (bid >> 3);
    const int mb = wg >> 6, nb = wg & 63;
    const int m0 = mb * 128, n0 = nb * 128;

    const int t = threadIdx.x;
    const int lane = t & 63, w = t >> 6;
    const int wm = w >> 1, wn = w & 1;
    const int fr = lane & 15, kb = lane >> 4;

    f32x4 acc[4][4] = {};

    for (int k0 = 0; k0 < DIM; k0 += 32) {
        #pragma unroll
        for (int p = 0; p < 2; ++p) {
            int ch = p * 256 + t;
            int r = ch >> 2, s = ch & 3;
            size_t go = (size_t)(m0 + r) * DIM + k0 + s * 8;
            size_t gn = (size_t)(n0 + r) * DIM + k0 + s * 8;
            *(int4*)&Ah[r][s * 8] = *(const int4*)&Qh[go];
            *(int4*)&Al[r][s * 8] = *(const int4*)&Ql[go];
            *(int4*)&Bh[r][s * 8] = *(const int4*)&Kh[gn];
            *(int4*)&Bl[r][s * 8] = *(const int4*)&Kl[gn];
        }
        __syncthreads();

        bf16x8 ah[4], al[4], bh[4], bl[4];
        #pragma unroll
        for (int m = 0; m < 4; ++m) {
            int row = wm * 64 + m * 16 + fr;
            ah[m] = *(const bf16x8*)&Ah[row][kb * 8];
            al[m] = *(const bf16x8*)&Al[row][kb * 8];
        }
        #pragma unroll
        for (int n = 0; n < 4; ++n) {
            int col = wn * 64 + n * 16 + fr;
            bh[n] = *(const bf16x8*)&Bh[col][kb * 8];
            bl[n] = *(const bf16x8*)&Bl[col][kb * 8];
        }
        #pragma unroll
        for (int m = 0; m < 4; ++m)
            #pragma unroll
            for (int n = 0; n < 4; ++n) {
                acc[m][n] = __builtin_amdgcn_mfma_f32_16x16x32_bf16(ah[m], bh[n], acc[m][n], 0, 0, 0);
                acc[m][n] = __builtin_amdgcn_mfma_f32_16x16x32_bf16(ah[m], bl[n], acc[m][n], 0, 0, 0);
                acc[m][n] = __builtin_amdgcn_mfma_f32_16x16x32_bf16(al[m], bh[n], acc[m][n], 0, 0, 0);
            }
        __syncthreads();
    }

    #pragma unroll
    for (int m = 0; m < 4; ++m)
        #pragma unroll
        for (int e = 0; e < 4; ++e) {
            int row = m0 + wm * 64 + m * 16 + (lane >> 4) * 4 + e;
            #pragma unroll
            for (int n = 0; n < 4; ++n) {
                int col = n0 + wn * 64 + n * 16 + fr;
                S[(size_t)row * N_NODES + col] = acc[m][n][e];
            }
        }
}

// ---------------------------------------------------------------------------
// Per-row max and 1/sum(exp(x-max)) of raw scores. One block per row.
// ---------------------------------------------------------------------------
__global__ __launch_bounds__(1024) void rowstat_kernel(
    const float* __restrict__ S, float2* __restrict__ rs)
{
    const int row = blockIdx.x;
    const float* rp = S + (size_t)row * N_NODES;
    const int t = threadIdx.x;

    float4 v0 = *(const float4*)(rp + t * 8);
    float4 v1 = *(const float4*)(rp + t * 8 + 4);
    float x[8] = {v0.x, v0.y, v0.z, v0.w, v1.x, v1.y, v1.z, v1.w};

    float m = x[0];
    #pragma unroll
    for (int i = 1; i < 8; ++i) m = fmaxf(m, x[i]);
    #pragma unroll
    for (int o = 32; o; o >>= 1) m = fmaxf(m, __shfl_xor(m, o));

    __shared__ float redm[16], reds[16];
    const int wid = t >> 6;
    if ((t & 63) == 0) redm[wid] = m;
    __syncthreads();
    float gm = redm[0];
    #pragma unroll
    for (int i = 1; i < 16; ++i) gm = fmaxf(gm, redm[i]);

    float s = 0.0f;
    #pragma unroll
    for (int i = 0; i < 8; ++i) s += __expf(x[i] - gm);
    #pragma unroll
    for (int o = 32; o; o >>= 1) s += __shfl_xor(s, o);
    if ((t & 63) == 0) reds[wid] = s;
    __syncthreads();
    if (t == 0) {
        float gs = 0.0f;
        #pragma unroll
        for (int i = 0; i < 16; ++i) gs += reds[i];
        rs[row] = make_float2(gm, 1.0f / gs);
    }
}

// ---------------------------------------------------------------------------
// Fused: read raw scores, normalize (exp(x-m)*inv_s), write attn fp32
// in place, and accumulate ZA = attn @ V via bf16 MFMA with VT.
// Block: 32 rows x all 256 cols, 4 waves, BK=64.
// ---------------------------------------------------------------------------
__global__ __launch_bounds__(256) void av_kernel(
    float* S, const float2* __restrict__ rs,
    const unsigned short* __restrict__ VT, float* __restrict__ ZA)
{
    __shared__ short As[32][72];
    __shared__ short Bs[256][72];
    __shared__ float sm[32], si[32];

    const int r0 = blockIdx.x * 32;
    const int t = threadIdx.x;
    const int lane = t & 63, wn = t >> 6;
    const int fr = lane & 15, kb = lane >> 4;

    if (t < 32) { float2 v = rs[r0 + t]; sm[t] = v.x; si[t] = v.y; }
    __syncthreads();

    f32x4 acc[2][4] = {};

    const int ar = t >> 3, sl = t & 7;
    const float m  = sm[ar];
    const float is = si[ar];
    float* arow = S + (size_t)(r0 + ar) * N_NODES + sl * 8;

    for (int k0 = 0; k0 < N_NODES; k0 += 64) {
        // ---- A: load scores, normalize, write attn, stage bf16
        float4 v0 = *(const float4*)(arow + k0);
        float4 v1 = *(const float4*)(arow + k0 + 4);
        float p[8] = {v0.x, v0.y, v0.z, v0.w, v1.x, v1.y, v1.z, v1.w};
        #pragma unroll
        for (int j = 0; j < 8; ++j) p[j] = __expf(p[j] - m) * is;
        *(float4*)(arow + k0)     = make_float4(p[0], p[1], p[2], p[3]);
        *(float4*)(arow + k0 + 4) = make_float4(p[4], p[5], p[6], p[7]);
        unsigned int w0 = (unsigned)f2bf(p[0]) | ((unsigned)f2bf(p[1]) << 16);
        unsigned int w1 = (unsigned)f2bf(p[2]) | ((unsigned)f2bf(p[3]) << 16);
        unsigned int w2 = (unsigned)f2bf(p[4]) | ((unsigned)f2bf(p[5]) << 16);
        unsigned int w3 = (unsigned)f2bf(p[6]) | ((unsigned)f2bf(p[7]) << 16);
        *(int4*)&As[ar][sl * 8] = make_int4(w0, w1, w2, w3);

        // ---- B: stage VT tile [256][64]
        #pragma unroll
        for (int pp = 0; pp < 8; ++pp) {
            int ch = pp * 256 + t;
            int c = ch >> 3, s2 = ch & 7;
            *(int4*)&Bs[c][s2 * 8] =
                *(const int4*)&VT[(size_t)c * N_NODES + k0 + s2 * 8];
        }
        __syncthreads();

        bf16x8 a[2][2], b[4][2];
        #pragma unroll
        for (int mm = 0; mm < 2; ++mm)
            #pragma unroll
            for (int h = 0; h < 2; ++h)
                a[mm][h] = *(const bf16x8*)&As[mm * 16 + fr][h * 32 + kb * 8];
        #pragma unroll
        for (int n = 0; n < 4; ++n)
            #pragma unroll
            for (int h = 0; h < 2; ++h)
                b[n][h] = *(const bf16x8*)&Bs[wn * 64 + n * 16 + fr][h * 32 + kb * 8];
        #pragma unroll
        for (int mm = 0; mm < 2; ++mm)
            #pragma unroll
            for (int n = 0; n < 4; ++n)
                #pragma unroll
                for (int h = 0; h < 2; ++h)
                    acc[mm][n] = __builtin_amdgcn_mfma_f32_16x16x32_bf16(
                        a[mm][h], b[n][h], acc[mm][n], 0, 0, 0);
        __syncthreads();
    }

    #pragma unroll
    for (int mm = 0; mm < 2; ++mm)
        #pragma unroll
        for (int e = 0; e < 4; ++e) {
            int row = r0 + mm * 16 + kb * 4 + e;
            #pragma unroll
            for (int n = 0; n < 4; ++n)
                ZA[(size_t)row * DIM + wn * 64 + n * 16 + fr] = acc[mm][n][e];
        }
}

// ---------------------------------------------------------------------------
// SpMM segment-sum (edge_row sorted; binary search, no atomics).
// ---------------------------------------------------------------------------
__global__ __launch_bounds__(256) void spmm_kernel(
    const float* __restrict__ H, const int* __restrict__ erow,
    const int* __restrict__ ecol, const float* __restrict__ ew,
    float* __restrict__ out, int E)
{
    const int node = blockIdx.x;
    const int t = threadIdx.x;

    int lo = 0, hi = E;
    while (lo < hi) { int mid = (lo + hi) >> 1; if (erow[mid] < node) lo = mid + 1; else hi = mid; }
    const int beg = lo;
    hi = E;
    while (lo < hi) { int mid = (lo + hi) >> 1; if (erow[mid] < node + 1) lo = mid + 1; else hi = mid; }
    const int end = lo;

    float acc = 0.0f;
    for (int e = beg; e < end; ++e)
        acc += ew[e] * H[(size_t)ecol[e] * DIM + t];
    out[(size_t)node * DIM + t] = acc;
}

// ---------------------------------------------------------------------------
__global__ __launch_bounds__(256) void blend_cls_kernel(
    const float* __restrict__ ZA, const float* __restrict__ GNN,
    const float* __restrict__ Wc, const float* __restrict__ bc,
    float* __restrict__ Y)
{
    const int row = blockIdx.x;
    const int t = threadIdx.x;
    __shared__ float z[DIM];
    __shared__ float part[4][NCLS];

    z[t] = 0.5f * (ZA[(size_t)row * DIM + t] + GNN[(size_t)row * DIM + t]);
    __syncthreads();

    if (t < 160) {
        const int c = t % NCLS, q = t / NCLS;
        float acc = 0.0f;
        #pragma unroll 4
        for (int d = q * 64; d < q * 64 + 64; ++d)
            acc += z[d] * Wc[d * NCLS + c];
        part[q][c] = acc;
    }
    __syncthreads();
    if (t < NCLS)
        Y[(size_t)row * NCLS + t] =
            part[0][t] + part[1][t] + part[2][t] + part[3][t] + bc[t];
}

// ---------------------------------------------------------------------------
extern "C" void kernel_launch(void* const* d_in, const int* in_sizes, int n_in,
                              void* d_out, int out_size, void* d_ws, size_t ws_size,
                              hipStream_t stream)
{
    const float* X     = (const float*)d_in[0];
    const int*   erow  = (const int*)d_in[1];
    const int*   ecol  = (const int*)d_in[2];
    const float* ew    = (const float*)d_in[3];
    const float* W_emb = (const float*)d_in[4];
    const float* b_emb = (const float*)d_in[5];
    const float* W_q   = (const float*)d_in[6];
    const float* b_q   = (const float*)d_in[7];
    const float* W_k   = (const float*)d_in[8];
    const float* b_k   = (const float*)d_in[9];
    const float* W_v   = (const float*)d_in[10];
    const float* b_v   = (const float*)d_in[11];
    const float* W_g   = (const float*)d_in[12];
    const float* b_g   = (const float*)d_in[13];
    const float* W_c   = (const float*)d_in[14];
    const float* b_c   = (const float*)d_in[15];
    const int E = in_sizes[1];

    float* Y    = (float*)d_out;                  // [N, C]
    float* attn = Y + (size_t)N_NODES * NCLS;     // [N, N] scores -> attn

    const size_t ND = (size_t)N_NODES * DIM;
    float* Z0  = (float*)d_ws;
    float* Qf  = Z0 + ND;
    float* Kf  = Qf + ND;
    float* Vf  = Kf + ND;
    float* Hf  = Vf + ND;
    float* ZA  = Hf + ND;
    float* GNN = ZA + ND;
    float2* rstat = (float2*)(GNN + ND);          // 8192 float2

    // region reuse (stream-serial ordering makes each safe):
    unsigned short* Qh = (unsigned short*)Z0;     // Z0 dead after projections
    unsigned short* Ql = Qh + ND;
    unsigned short* Kh = (unsigned short*)ZA;     // ZA written only by av (after qkt)
    unsigned short* Kl = Kh + ND;
    unsigned short* VT = (unsigned short*)GNN;    // GNN written by spmm (after av)

    // 1. Z0 = X @ W_emb + b_emb
    gemm_kernel<128, 64, 16, 8, 4, false>
        <<<dim3(DIM / 64, N_NODES / 128), 256, 0, stream>>>(
            X, W_emb, b_emb, Z0, N_NODES, DIM, F_IN);

    // 2. projections (all read Z0, must precede ln_split into Z0 region)
    gemm_kernel<128, 64, 16, 8, 4, false>
        <<<dim3(DIM / 64, N_NODES / 128), 256, 0, stream>>>(
            Z0, W_q, b_q, Qf, N_NODES, DIM, DIM);
    gemm_kernel<128, 64, 16, 8, 4, false>
        <<<dim3(DIM / 64, N_NODES / 128), 256, 0, stream>>>(
            Z0, W_k, b_k, Kf, N_NODES, DIM, DIM);
    gemm_kernel<128, 64, 16, 8, 4, false>
        <<<dim3(DIM / 64, N_NODES / 128), 256, 0, stream>>>(
            Z0, W_v, b_v, Vf, N_NODES, DIM, DIM);
    gemm_kernel<128, 64, 16, 8, 4, false>
        <<<dim3(DIM / 64, N_NODES / 128), 256, 0, stream>>>(
            Z0, W_g, b_g, Hf, N_NODES, DIM, DIM);

    // 3. LN + hi/lo bf16 split
    ln_split_kernel<<<N_NODES, 256, 0, stream>>>(Qf, Qh, Ql);
    ln_split_kernel<<<N_NODES, 256, 0, stream>>>(Kf, Kh, Kl);

    // 4. V -> VT bf16 transpose
    vtrans_kernel<<<dim3(N_NODES / 64, DIM / 64), 256, 0, stream>>>(Vf, VT);

    // 5. scores = Q @ K^T (split-bf16 MFMA)
    qkt_kernel<<<4096, 256, 0, stream>>>(Qh, Ql, Kh, Kl, attn);

    // 6. per-row softmax stats
    rowstat_kernel<<<N_NODES, 1024, 0, stream>>>(attn, rstat);

    // 7. fused normalize + attn write + ZA = attn @ V
    av_kernel<<<N_NODES / 32, 256, 0, stream>>>(attn, rstat, VT, ZA);

    // 8. GNN branch (after av: GNN region held VT)
    spmm_kernel<<<N_NODES, 256, 0, stream>>>(Hf, erow, ecol, ew, GNN, E);

    // 9. blend + classifier
    blend_cls_kernel<<<N_NODES, 256, 0, stream>>>(ZA, GNN, W_c, b_c, Y);
}

// Round 3
// 673.342 us; speedup vs baseline: 2.2001x; 1.1144x over previous
//
#include <hip/hip_runtime.h>
#include <hip/hip_bf16.h>

#define N_NODES 8192
#define F_IN    512
#define DIM     256
#define NCLS    40

typedef __attribute__((ext_vector_type(8))) short bf16x8;
typedef __attribute__((ext_vector_type(4))) float f32x4;

#define MFMA16 __builtin_amdgcn_mfma_f32_16x16x32_bf16

static __device__ __forceinline__ unsigned short f2bf(float x) {
    __hip_bfloat16 h = __float2bfloat16(x);
    return *reinterpret_cast<unsigned short*>(&h);
}
static __device__ __forceinline__ float bf2f(unsigned short u) {
    union { unsigned int u32; float f; } v; v.u32 = ((unsigned int)u) << 16;
    return v.f;
}
static __device__ __forceinline__ void gll16(const void* g, void* l) {
    __builtin_amdgcn_global_load_lds(
        (const __attribute__((address_space(1))) unsigned int*)g,
        (__attribute__((address_space(3))) unsigned int*)l, 16, 0, 0);
}

// ---------------------------------------------------------------------------
// fp32 tiled GEMM for the projections. OBF=true writes bf16 output.
// ---------------------------------------------------------------------------
template<int BM, int BN, int BK, int TM, int TN, bool OBF>
__global__ __launch_bounds__(256) void gemm_kernel(
    const float* __restrict__ A, const float* __restrict__ B,
    const float* __restrict__ bias, float* __restrict__ C,
    int M, int N, int K)
{
    static_assert((BM / TM) * (BN / TN) == 256, "256 threads");

    __shared__ float As[BK][BM];
    __shared__ float Bs[BK][BN];

    const int tid = threadIdx.x;
    const int tx  = tid % (BN / TN);
    const int ty  = tid / (BN / TN);
    const int n0  = blockIdx.x * BN;
    const int m0  = blockIdx.y * BM;

    float acc[TM][TN] = {};

    for (int k0 = 0; k0 < K; k0 += BK) {
        #pragma unroll
        for (int i = tid * 4; i < BM * BK; i += 1024) {
            int r = i / BK, c = i % BK;
            float4 v = *(const float4*)(A + (size_t)(m0 + r) * K + k0 + c);
            As[c + 0][r] = v.x; As[c + 1][r] = v.y;
            As[c + 2][r] = v.z; As[c + 3][r] = v.w;
        }
        #pragma unroll
        for (int i = tid * 4; i < BK * BN; i += 1024) {
            int r = i / BN, c = i % BN;
            *(float4*)&Bs[r][c] =
                *(const float4*)(B + (size_t)(k0 + r) * N + n0 + c);
        }
        __syncthreads();

        #pragma unroll
        for (int k = 0; k < BK; ++k) {
            float a[TM], b[TN];
            #pragma unroll
            for (int i = 0; i < TM; i += 4)
                *(float4*)&a[i] = *(const float4*)&As[k][ty * TM + i];
            #pragma unroll
            for (int j = 0; j < TN; j += 4)
                *(float4*)&b[j] = *(const float4*)&Bs[k][tx * TN + j];
            #pragma unroll
            for (int i = 0; i < TM; ++i)
                #pragma unroll
                for (int j = 0; j < TN; ++j)
                    acc[i][j] += a[i] * b[j];
        }
        __syncthreads();
    }

    #pragma unroll
    for (int i = 0; i < TM; ++i) {
        const int m = m0 + ty * TM + i;
        #pragma unroll
        for (int j = 0; j < TN; ++j) {
            const int n = n0 + tx * TN + j;
            float v = acc[i][j];
            if (bias) v += bias[n];
            if (OBF) ((unsigned short*)C)[(size_t)m * N + n] = f2bf(v);
            else     C[(size_t)m * N + n] = v;
        }
    }
}

// ---------------------------------------------------------------------------
// LayerNorm + hi/lo bf16 split.
// ---------------------------------------------------------------------------
__global__ __launch_bounds__(256) void ln_split_kernel(
    const float* __restrict__ X,
    unsigned short* __restrict__ Hi, unsigned short* __restrict__ Lo)
{
    const int row = blockIdx.x;
    const int t = threadIdx.x;
    float x = X[(size_t)row * DIM + t];

    float s1 = x, s2 = x * x;
    #pragma unroll
    for (int o = 32; o; o >>= 1) {
        s1 += __shfl_xor(s1, o);
        s2 += __shfl_xor(s2, o);
    }
    __shared__ float r1[4], r2[4];
    const int wid = t >> 6;
    if ((t & 63) == 0) { r1[wid] = s1; r2[wid] = s2; }
    __syncthreads();
    const float sum = r1[0] + r1[1] + r1[2] + r1[3];
    const float ssq = r2[0] + r2[1] + r2[2] + r2[3];
    const float mean = sum * (1.0f / DIM);
    const float var  = ssq * (1.0f / DIM) - mean * mean;
    const float y = (x - mean) * rsqrtf(var + 1e-5f);

    const unsigned short h = f2bf(y);
    Hi[(size_t)row * DIM + t] = h;
    Lo[(size_t)row * DIM + t] = f2bf(y - bf2f(h));
}

// ---------------------------------------------------------------------------
// V [8192,256] fp32 -> VT [256,8192] bf16.
// ---------------------------------------------------------------------------
__global__ __launch_bounds__(256) void vtrans_kernel(
    const float* __restrict__ V, unsigned short* __restrict__ VT)
{
    __shared__ float tile[64][65];
    const int r0 = blockIdx.x * 64;
    const int c0 = blockIdx.y * 64;
    const int t = threadIdx.x;
    #pragma unroll
    for (int i = 0; i < 4; ++i) {
        int r = i * 16 + (t >> 4);
        int c = (t & 15) * 4;
        float4 v = *(const float4*)&V[(size_t)(r0 + r) * DIM + c0 + c];
        tile[r][c] = v.x; tile[r][c + 1] = v.y;
        tile[r][c + 2] = v.z; tile[r][c + 3] = v.w;
    }
    __syncthreads();
    #pragma unroll
    for (int i = 0; i < 4; ++i) {
        int c = i * 16 + (t >> 4);
        int r = (t & 15) * 4;
        ushort4 o;
        o.x = f2bf(tile[r][c]);     o.y = f2bf(tile[r + 1][c]);
        o.z = f2bf(tile[r + 2][c]); o.w = f2bf(tile[r + 3][c]);
        *(ushort4*)&VT[(size_t)(c0 + c) * N_NODES + r0 + r] = o;
    }
}

// ---------------------------------------------------------------------------
// scores = Q @ K^T (split-bf16, 3 MFMA terms), m97-style global_load_lds
// staging, fused per-block softmax partial stats -> pstat[row][colblock].
// ---------------------------------------------------------------------------
__global__ __launch_bounds__(256) void qkt_kernel(
    const unsigned short* __restrict__ Qh, const unsigned short* __restrict__ Ql,
    const unsigned short* __restrict__ Kh, const unsigned short* __restrict__ Kl,
    float* __restrict__ S, float2* __restrict__ pstat)
{
    __shared__ short Ah[128][32], Al[128][32], Bh[128][32], Bl[128][32];
    __shared__ float2 ps[2][128];

    const int bid = blockIdx.x;
    const int wg = (bid & 7) * 512 + (bid >> 3);   // XCD swizzle (4096%8==0)
    const int mb = wg >> 6, nb = wg & 63;
    const int m0 = mb * 128, n0 = nb * 128;

    const int t = threadIdx.x, lane = t & 63, w = t >> 6;
    const int wm = w >> 1, wn = w & 1;
    const int fr = lane & 15, kb = lane >> 4;

    f32x4 acc[4][4] = {};

    for (int k0 = 0; k0 < DIM; k0 += 32) {
        #pragma unroll
        for (int r = 0; r < 2; ++r) {
            int c = r * 256 + t;
            int row = c >> 2, slot = c & 3;
            size_t ga = (size_t)(m0 + row) * DIM + k0 + slot * 8;
            size_t gb = (size_t)(n0 + row) * DIM + k0 + slot * 8;
            int lo = c * 16;
            gll16(Qh + ga, (char*)&Ah[0][0] + lo);
            gll16(Ql + ga, (char*)&Al[0][0] + lo);
            gll16(Kh + gb, (char*)&Bh[0][0] + lo);
            gll16(Kl + gb, (char*)&Bl[0][0] + lo);
        }
        __syncthreads();

        bf16x8 ah[4], al[4], bh[4], bl[4];
        #pragma unroll
        for (int m = 0; m < 4; ++m) {
            int row = wm * 64 + m * 16 + fr;
            ah[m] = *(const bf16x8*)&Ah[row][kb * 8];
            al[m] = *(const bf16x8*)&Al[row][kb * 8];
        }
        #pragma unroll
        for (int n = 0; n < 4; ++n) {
            int col = wn * 64 + n * 16 + fr;
            bh[n] = *(const bf16x8*)&Bh[col][kb * 8];
            bl[n] = *(const bf16x8*)&Bl[col][kb * 8];
        }
        #pragma unroll
        for (int m = 0; m < 4; ++m)
            #pragma unroll
            for (int n = 0; n < 4; ++n) {
                acc[m][n] = MFMA16(ah[m], bh[n], acc[m][n], 0, 0, 0);
                acc[m][n] = MFMA16(ah[m], bl[n], acc[m][n], 0, 0, 0);
                acc[m][n] = MFMA16(al[m], bh[n], acc[m][n], 0, 0, 0);
            }
        __syncthreads();
    }

    // ---- write raw scores
    #pragma unroll
    for (int m = 0; m < 4; ++m)
        #pragma unroll
        for (int e = 0; e < 4; ++e) {
            int row = m0 + wm * 64 + m * 16 + kb * 4 + e;
            #pragma unroll
            for (int n = 0; n < 4; ++n)
                S[(size_t)row * N_NODES + n0 + wn * 64 + n * 16 + fr] =
                    acc[m][n][e];
        }

    // ---- per-row (max, sumexp) over this block's 128 cols
    #pragma unroll
    for (int m = 0; m < 4; ++m)
        #pragma unroll
        for (int e = 0; e < 4; ++e) {
            float mx = acc[m][0][e];
            #pragma unroll
            for (int n = 1; n < 4; ++n) mx = fmaxf(mx, acc[m][n][e]);
            #pragma unroll
            for (int o = 1; o < 16; o <<= 1) mx = fmaxf(mx, __shfl_xor(mx, o));
            float se = 0.f;
            #pragma unroll
            for (int n = 0; n < 4; ++n) se += __expf(acc[m][n][e] - mx);
            #pragma unroll
            for (int o = 1; o < 16; o <<= 1) se += __shfl_xor(se, o);
            if (fr == 0) ps[wn][wm * 64 + m * 16 + kb * 4 + e] = make_float2(mx, se);
        }
    __syncthreads();
    if (t < 128) {
        float2 a = ps[0][t], b = ps[1][t];
        float gm = fmaxf(a.x, b.x);
        float gs = a.y * __expf(a.x - gm) + b.y * __expf(b.x - gm);
        pstat[(size_t)(m0 + t) * 64 + nb] = make_float2(gm, gs);
    }
}

// ---------------------------------------------------------------------------
// rstat[row] = (gmax, 1/gsum) from 64 pstat entries. 4 rows/block.
// ---------------------------------------------------------------------------
__global__ __launch_bounds__(256) void rstat_reduce_kernel(
    const float2* __restrict__ pstat, float2* __restrict__ rstat)
{
    const int row = blockIdx.x * 4 + (threadIdx.x >> 6);
    const int lane = threadIdx.x & 63;
    float2 v = pstat[(size_t)row * 64 + lane];
    float gm = v.x;
    #pragma unroll
    for (int o = 1; o < 64; o <<= 1) gm = fmaxf(gm, __shfl_xor(gm, o));
    float s = v.y * __expf(v.x - gm);
    #pragma unroll
    for (int o = 1; o < 64; o <<= 1) s += __shfl_xor(s, o);
    if (lane == 0) rstat[row] = make_float2(gm, 1.0f / s);
}

// ---------------------------------------------------------------------------
// Fused normalize + attn write + partial ZA. Grid (256 rowblocks, 4 ksplit).
// B fragments read directly from L2-resident VT (no LDS B tile).
// ---------------------------------------------------------------------------
static __device__ __forceinline__ void norm_pack(
    float* dst, unsigned short* lds,
    float4 v0, float4 v1, float4 v2, float4 v3, float m, float inv)
{
    float p[16] = {v0.x, v0.y, v0.z, v0.w, v1.x, v1.y, v1.z, v1.w,
                   v2.x, v2.y, v2.z, v2.w, v3.x, v3.y, v3.z, v3.w};
    #pragma unroll
    for (int j = 0; j < 16; ++j) p[j] = __expf(p[j] - m) * inv;
    *(float4*)(dst + 0)  = make_float4(p[0], p[1], p[2], p[3]);
    *(float4*)(dst + 4)  = make_float4(p[4], p[5], p[6], p[7]);
    *(float4*)(dst + 8)  = make_float4(p[8], p[9], p[10], p[11]);
    *(float4*)(dst + 12) = make_float4(p[12], p[13], p[14], p[15]);
    unsigned int u[8];
    #pragma unroll
    for (int j = 0; j < 8; ++j)
        u[j] = (unsigned)f2bf(p[2 * j]) | ((unsigned)f2bf(p[2 * j + 1]) << 16);
    *(int4*)(lds)     = make_int4(u[0], u[1], u[2], u[3]);
    *(int4*)(lds + 8) = make_int4(u[4], u[5], u[6], u[7]);
}

__global__ __launch_bounds__(256) void av_kernel(
    float* S, const float2* __restrict__ rs, const unsigned short* __restrict__ VT,
    float* __restrict__ P0, float* __restrict__ P1,
    float* __restrict__ P2, float* __restrict__ P3)
{
    __shared__ unsigned short As[2][32][128];
    __shared__ float sm[32], si[32];

    const int r0 = blockIdx.x * 32;
    const int ks = blockIdx.y;
    const int kbase = ks * 2048;
    const int t = threadIdx.x, lane = t & 63, w = t >> 6;
    const int fr = lane & 15, kb = lane >> 4;

    if (t < 32) { float2 v = rs[r0 + t]; sm[t] = v.x; si[t] = v.y; }
    __syncthreads();

    const int ar = t >> 3, sl = t & 7;
    const float m = sm[ar], inv = si[ar];
    float* arow = S + (size_t)(r0 + ar) * N_NODES + kbase + sl * 16;

    const unsigned short* vbase[4];
    #pragma unroll
    for (int n = 0; n < 4; ++n)
        vbase[n] = VT + (size_t)(w * 64 + n * 16 + fr) * N_NODES + kbase + kb * 8;

    f32x4 acc[2][4] = {};

    {   // stage step 0
        float4 v0 = *(const float4*)(arow + 0);
        float4 v1 = *(const float4*)(arow + 4);
        float4 v2 = *(const float4*)(arow + 8);
        float4 v3 = *(const float4*)(arow + 12);
        norm_pack(arow, &As[0][ar][sl * 16], v0, v1, v2, v3, m, inv);
    }
    __syncthreads();

    for (int s = 0; s < 16; ++s) {
        const int b = s & 1;
        const bool more = (s + 1 < 16);
        float4 w0, w1, w2, w3;
        if (more) {
            const float* nx = arow + (s + 1) * 128;
            w0 = *(const float4*)(nx + 0);
            w1 = *(const float4*)(nx + 4);
            w2 = *(const float4*)(nx + 8);
            w3 = *(const float4*)(nx + 12);
        }
        #pragma unroll
        for (int ksl = 0; ksl < 4; ++ksl) {
            bf16x8 a0 = *(const bf16x8*)&As[b][fr][ksl * 32 + kb * 8];
            bf16x8 a1 = *(const bf16x8*)&As[b][16 + fr][ksl * 32 + kb * 8];
            #pragma unroll
            for (int n = 0; n < 4; ++n) {
                bf16x8 bb = *(const bf16x8*)(vbase[n] + s * 128 + ksl * 32);
                acc[0][n] = MFMA16(a0, bb, acc[0][n], 0, 0, 0);
                acc[1][n] = MFMA16(a1, bb, acc[1][n], 0, 0, 0);
            }
        }
        if (more)
            norm_pack(arow + (s + 1) * 128, &As[b ^ 1][ar][sl * 16],
                      w0, w1, w2, w3, m, inv);
        __syncthreads();
    }

    float* P = (ks == 0) ? P0 : (ks == 1) ? P1 : (ks == 2) ? P2 : P3;
    #pragma unroll
    for (int mm = 0; mm < 2; ++mm)
        #pragma unroll
        for (int e = 0; e < 4; ++e) {
            int row = r0 + mm * 16 + kb * 4 + e;
            #pragma unroll
            for (int n = 0; n < 4; ++n)
                P[(size_t)row * DIM + w * 64 + n * 16 + fr] = acc[mm][n][e];
        }
}

// ---------------------------------------------------------------------------
__global__ __launch_bounds__(256) void za_reduce_kernel(
    const float* __restrict__ p0, const float* __restrict__ p1,
    const float* __restrict__ p2, const float* __restrict__ p3,
    float* __restrict__ ZA)
{
    size_t i = ((size_t)blockIdx.x * 256 + threadIdx.x) * 4;
    float4 a = *(const float4*)(p0 + i);
    float4 b = *(const float4*)(p1 + i);
    float4 c = *(const float4*)(p2 + i);
    float4 d = *(const float4*)(p3 + i);
    *(float4*)(ZA + i) = make_float4(a.x + b.x + c.x + d.x,
                                     a.y + b.y + c.y + d.y,
                                     a.z + b.z + c.z + d.z,
                                     a.w + b.w + c.w + d.w);
}

// ---------------------------------------------------------------------------
// SpMM: one 64-lane wave per node, lane holds 4 features (ushort4 loads).
// ---------------------------------------------------------------------------
__global__ __launch_bounds__(256) void spmm_kernel(
    const unsigned short* __restrict__ Hb, const int* __restrict__ erow,
    const int* __restrict__ ecol, const float* __restrict__ ew,
    float* __restrict__ out, int E)
{
    const int node = blockIdx.x * 4 + (threadIdx.x >> 6);
    const int lane = threadIdx.x & 63;

    int lo = 0, hi = E;
    while (lo < hi) { int mid = (lo + hi) >> 1; if (erow[mid] < node) lo = mid + 1; else hi = mid; }
    const int beg = lo;
    hi = E;
    while (lo < hi) { int mid = (lo + hi) >> 1; if (erow[mid] < node + 1) lo = mid + 1; else hi = mid; }
    const int end = lo;

    float4 acc = make_float4(0.f, 0.f, 0.f, 0.f);
    for (int e = beg; e < end; ++e) {
        const int col = ecol[e];
        const float wgt = ew[e];
        ushort4 h = *(const ushort4*)&Hb[(size_t)col * DIM + lane * 4];
        acc.x += wgt * bf2f(h.x);
        acc.y += wgt * bf2f(h.y);
        acc.z += wgt * bf2f(h.z);
        acc.w += wgt * bf2f(h.w);
    }
    *(float4*)&out[(size_t)node * DIM + lane * 4] = acc;
}

// ---------------------------------------------------------------------------
__global__ __launch_bounds__(256) void blend_cls_kernel(
    const float* __restrict__ ZA, const float* __restrict__ GNN,
    const float* __restrict__ Wc, const float* __restrict__ bc,
    float* __restrict__ Y)
{
    const int row = blockIdx.x;
    const int t = threadIdx.x;
    __shared__ float z[DIM];
    __shared__ float part[4][NCLS];

    z[t] = 0.5f * (ZA[(size_t)row * DIM + t] + GNN[(size_t)row * DIM + t]);
    __syncthreads();

    if (t < 160) {
        const int c = t % NCLS, q = t / NCLS;
        float acc = 0.0f;
        #pragma unroll 4
        for (int d = q * 64; d < q * 64 + 64; ++d)
            acc += z[d] * Wc[d * NCLS + c];
        part[q][c] = acc;
    }
    __syncthreads();
    if (t < NCLS)
        Y[(size_t)row * NCLS + t] =
            part[0][t] + part[1][t] + part[2][t] + part[3][t] + bc[t];
}

// ---------------------------------------------------------------------------
extern "C" void kernel_launch(void* const* d_in, const int* in_sizes, int n_in,
                              void* d_out, int out_size, void* d_ws, size_t ws_size,
                              hipStream_t stream)
{
    const float* X     = (const float*)d_in[0];
    const int*   erow  = (const int*)d_in[1];
    const int*   ecol  = (const int*)d_in[2];
    const float* ew    = (const float*)d_in[3];
    const float* W_emb = (const float*)d_in[4];
    const float* b_emb = (const float*)d_in[5];
    const float* W_q   = (const float*)d_in[6];
    const float* b_q   = (const float*)d_in[7];
    const float* W_k   = (const float*)d_in[8];
    const float* b_k   = (const float*)d_in[9];
    const float* W_v   = (const float*)d_in[10];
    const float* b_v   = (const float*)d_in[11];
    const float* W_g   = (const float*)d_in[12];
    const float* b_g   = (const float*)d_in[13];
    const float* W_c   = (const float*)d_in[14];
    const float* b_c   = (const float*)d_in[15];
    const int E = in_sizes[1];

    float* Y    = (float*)d_out;
    float* Sc   = Y + (size_t)N_NODES * NCLS;      // scores -> attn [N,N]

    const size_t ND = (size_t)N_NODES * DIM;
    float* R0 = (float*)d_ws;      // Z0, later: VT (4MB) + pstat (4MB)
    float* R1 = R0 + ND;           // Qf, later ZA partial 0
    float* R2 = R1 + ND;           // Kf, later ZA partial 1
    float* R3 = R2 + ND;           // Vf, later ZA partial 2
    float* R4 = R3 + ND;           // Hb (bf16, 4MB) + rstat
    float* R5 = R4 + ND;           // Qh/Ql, later ZA
    float* R6 = R5 + ND;           // Kh/Kl, later ZA partial 3, then GNN

    unsigned short* Qh = (unsigned short*)R5;
    unsigned short* Ql = Qh + ND;
    unsigned short* Kh = (unsigned short*)R6;
    unsigned short* Kl = Kh + ND;
    unsigned short* VT = (unsigned short*)R0;
    unsigned short* Hb = (unsigned short*)R4;
    float2* pstat = (float2*)(R0 + ND / 2);        // 8192 x 64 float2 = 4MB
    float2* rstat = (float2*)(R4 + ND / 2);        // 8192 float2

    // 1. Z0 = X @ W_emb + b_emb
    gemm_kernel<128, 64, 16, 8, 4, false>
        <<<dim3(DIM / 64, N_NODES / 128), 256, 0, stream>>>(
            X, W_emb, b_emb, R0, N_NODES, DIM, F_IN);

    // 2. projections from Z0
    gemm_kernel<128, 64, 16, 8, 4, false>
        <<<dim3(DIM / 64, N_NODES / 128), 256, 0, stream>>>(
            R0, W_q, b_q, R1, N_NODES, DIM, DIM);
    gemm_kernel<128, 64, 16, 8, 4, false>
        <<<dim3(DIM / 64, N_NODES / 128), 256, 0, stream>>>(
            R0, W_k, b_k, R2, N_NODES, DIM, DIM);
    gemm_kernel<128, 64, 16, 8, 4, false>
        <<<dim3(DIM / 64, N_NODES / 128), 256, 0, stream>>>(
            R0, W_v, b_v, R3, N_NODES, DIM, DIM);
    gemm_kernel<128, 64, 16, 8, 4, true>
        <<<dim3(DIM / 64, N_NODES / 128), 256, 0, stream>>>(
            R0, W_g, b_g, (float*)Hb, N_NODES, DIM, DIM);

    // 3. LN + hi/lo split
    ln_split_kernel<<<N_NODES, 256, 0, stream>>>(R1, Qh, Ql);
    ln_split_kernel<<<N_NODES, 256, 0, stream>>>(R2, Kh, Kl);

    // 4. V -> VT bf16 (Z0/R0 dead now)
    vtrans_kernel<<<dim3(N_NODES / 64, DIM / 64), 256, 0, stream>>>(R3, VT);

    // 5. scores + fused softmax partial stats
    qkt_kernel<<<4096, 256, 0, stream>>>(Qh, Ql, Kh, Kl, Sc, pstat);

    // 6. reduce partial stats -> per-row (max, 1/sum)
    rstat_reduce_kernel<<<N_NODES / 4, 256, 0, stream>>>(pstat, rstat);

    // 7. fused normalize + attn write + partial ZA (k-split 4)
    av_kernel<<<dim3(N_NODES / 32, 4), 256, 0, stream>>>(
        Sc, rstat, VT, R1, R2, R3, R6);

    // 8. ZA = sum of partials
    za_reduce_kernel<<<ND / 1024, 256, 0, stream>>>(R1, R2, R3, R6, R5);

    // 9. GNN branch (bf16 H)
    spmm_kernel<<<N_NODES / 4, 256, 0, stream>>>(Hb, erow, ecol, ew, R6, E);

    // 10. blend + classifier
    blend_cls_kernel<<<N_NODES, 256, 0, stream>>>(R5, R6, W_c, b_c, Y);
}